// Round 3
// baseline (425.267 us; speedup 1.0000x reference)
//
#include <hip/hip_runtime.h>

#define NH 4
#define HD 128
#define BS 32
#define STRIDE 16

typedef float  floatx4 __attribute__((ext_vector_type(4)));
typedef __bf16 bf16x8  __attribute__((ext_vector_type(8)));
typedef __bf16 bf16x2  __attribute__((ext_vector_type(2)));
typedef unsigned short u16x8 __attribute__((ext_vector_type(8)));

__device__ __forceinline__ unsigned short f2bf(float f) {
  unsigned u = __builtin_bit_cast(unsigned, f);
  u += 0x7FFFu + ((u >> 16) & 1u);   // RTNE (inputs finite)
  return (unsigned short)(u >> 16);
}

__device__ __forceinline__ bf16x8 cvt8(float4 lo, float4 hi) {
  bf16x8 r;
#if __has_builtin(__builtin_amdgcn_cvt_pk_bf16_f32)
  bf16x2 p0 = __builtin_bit_cast(bf16x2, __builtin_amdgcn_cvt_pk_bf16_f32(lo.x, lo.y));
  bf16x2 p1 = __builtin_bit_cast(bf16x2, __builtin_amdgcn_cvt_pk_bf16_f32(lo.z, lo.w));
  bf16x2 p2 = __builtin_bit_cast(bf16x2, __builtin_amdgcn_cvt_pk_bf16_f32(hi.x, hi.y));
  bf16x2 p3 = __builtin_bit_cast(bf16x2, __builtin_amdgcn_cvt_pk_bf16_f32(hi.z, hi.w));
  r[0] = p0[0]; r[1] = p0[1]; r[2] = p1[0]; r[3] = p1[1];
  r[4] = p2[0]; r[5] = p2[1]; r[6] = p3[0]; r[7] = p3[1];
#else
  u16x8 t;
  t[0] = f2bf(lo.x); t[1] = f2bf(lo.y); t[2] = f2bf(lo.z); t[3] = f2bf(lo.w);
  t[4] = f2bf(hi.x); t[5] = f2bf(hi.y); t[6] = f2bf(hi.z); t[7] = f2bf(hi.w);
  r = __builtin_bit_cast(bf16x8, t);
#endif
  return r;
}

// Prep: LDS-tiled transpose of w into wt layout [mat][j][k0][fq][e][dq] (bf16).
// Block 256 (last) writes the cu_out prefix tail.
__global__ void prep_kernel(const float* __restrict__ wk, const float* __restrict__ wv,
                            unsigned short* __restrict__ wt,
                            const int* __restrict__ cu, int num_seqs,
                            float* __restrict__ tail) {
  const int bx = blockIdx.x;
  if (bx == 2 * BS * 4) {
    if (threadIdx.x == 0) {
      int acc = 0;
      tail[0] = 0.0f;
      for (int b = 0; b < num_seqs; ++b) {
        int n = cu[b + 1] - cu[b];
        acc += (n - BS) / STRIDE;
        tail[b + 1] = (float)acc;
      }
    }
    return;
  }
  const int mat = bx >> 7;
  const int j   = (bx >> 2) & 31;
  const int k0  = bx & 3;
  const float* __restrict__ w =
      (mat ? wv : wk) + (size_t)j * (HD * HD) + (size_t)k0 * 32 * HD;
  __shared__ unsigned short tile[32][HD];
  const int t = threadIdx.x;
  const int r = t >> 3, c = (t & 7) * 16;
#pragma unroll
  for (int i = 0; i < 16; i += 4) {
    float4 f = *(const float4*)(w + r * HD + c + i);
    tile[r][c + i + 0] = f2bf(f.x);
    tile[r][c + i + 1] = f2bf(f.y);
    tile[r][c + i + 2] = f2bf(f.z);
    tile[r][c + i + 3] = f2bf(f.w);
  }
  __syncthreads();
  unsigned short* dst =
      wt + (size_t)mat * (BS * HD * HD) + (size_t)j * 16384 + k0 * 4096;
#pragma unroll
  for (int it = 0; it < 2; ++it) {
    int fi = t + it * 256;      // 0..511 over (fq, e)
    int fq = fi >> 7, e = fi & 127;
    u16x8 fr;
#pragma unroll
    for (int dq = 0; dq < 8; ++dq) fr[dq] = tile[fq * 8 + dq][e];
    *(u16x8*)(dst + fq * 1024 + e * 8) = fr;
  }
}

// Main GEMM, v4: NO LDS, NO barriers, NO inline asm in the K-loop.
// Weights (2 MB) are L2-resident; the per-step B working set (32 KB) is
// L1-sized and shared by the block's 4 waves -> read B fragments directly
// from global into registers. A prefetched 1 step deep in registers.
// Wave = 32m x 64n (2 m-frags x 4 n-frags, B reused x2); block = 4 waves
// = 64m x 128n; grid 510 -> 2 blocks/CU, 8 waves/CU. Compiler schedules
// freely (its waitcnt tracking stays intact: no asm, no LDS aliasing).
// K-order (j asc, k0 asc) identical -> bit-identical output.
__global__ __launch_bounds__(256, 2) void kvc_gemm(
    const float* __restrict__ kp, const float* __restrict__ vp,
    const unsigned short* __restrict__ wt, const int* __restrict__ cu,
    float* __restrict__ out, long out_half, int M_total, int num_seqs) {

  const int mat = blockIdx.y;
  const float* __restrict__ x = mat ? vp : kp;
  const unsigned short* __restrict__ wmat = wt + (size_t)mat * (BS * HD * HD);
  float* __restrict__ outp = out + (size_t)mat * out_half;

  const int tid = threadIdx.x, wid = tid >> 6, lane = tid & 63;
  const int fl = lane & 15, fq = lane >> 4;
  const int mw  = wid & 1;        // m-half within block
  const int nh  = wid >> 1;       // n-half within block
  const int ehw = nh * 64;
  const int mbase = blockIdx.x * 64 + mw * 32;

  // Per-lane token bases for the two 16-row m-fragments.
  const float* arow[2];
#pragma unroll
  for (int mf = 0; mf < 2; ++mf) {
    int m = mbase + mf * 16 + fl;
    int mc = m < M_total ? m : M_total - 1;
    int o = mc >> 2, h = mc & 3;
    int tb = 0, accb = 0;
    for (int b = 0; b < num_seqs; ++b) {
      int c0 = cu[b], c1 = cu[b + 1];
      int ol = (c1 - c0 - BS) / STRIDE;
      if (o >= accb && o - accb < ol) tb = c0 + (o - accb) * STRIDE;
      accb += ol;
    }
    arow[mf] = x + ((size_t)tb * NH + h) * HD + fq * 8;
  }

  floatx4 acc[2][4];
#pragma unroll
  for (int mf = 0; mf < 2; ++mf)
#pragma unroll
    for (int ni = 0; ni < 4; ++ni) acc[mf][ni] = (floatx4){0.f, 0.f, 0.f, 0.f};

  float4 raw[2][8];   // in-flight A for the NEXT j (16 dwordx4)

#define ALOAD(JN)                                                           \
  {                                                                         \
    _Pragma("unroll") for (int mf_ = 0; mf_ < 2; ++mf_) {                   \
      const float* ar_ = arow[mf_] + (size_t)(JN) * (NH * HD);              \
      _Pragma("unroll") for (int k_ = 0; k_ < 4; ++k_) {                    \
        raw[mf_][2 * k_]     = *(const float4*)(ar_ + k_ * 32);             \
        raw[mf_][2 * k_ + 1] = *(const float4*)(ar_ + k_ * 32 + 4);         \
      }                                                                     \
    }                                                                       \
  }

  ALOAD(0);

#pragma unroll 2
  for (int j = 0; j < BS; ++j) {
    // Convert current A (frees raw for the next prefetch).
    bf16x8 af[2][4];
#pragma unroll
    for (int mf = 0; mf < 2; ++mf)
#pragma unroll
      for (int k = 0; k < 4; ++k)
        af[mf][k] = cvt8(raw[mf][2 * k], raw[mf][2 * k + 1]);

    // Issue B fragment loads for this j (L1/L2 hits; 1 KB coalesced/instr).
    const unsigned short* bp = wmat + (size_t)j * 16384 + fq * 1024 +
                               (ehw + fl) * 8;
    bf16x8 b[4][4];
#pragma unroll
    for (int k = 0; k < 4; ++k)
#pragma unroll
      for (int ni = 0; ni < 4; ++ni)
        b[k][ni] = *(const bf16x8*)(bp + k * 4096 + ni * 128);

    // Prefetch A for next j (clamped; redundant last-iter load is harmless).
    const int jn = (j + 1 < BS) ? j + 1 : BS - 1;
    ALOAD(jn);

    // 32 MFMA: k0 ascending per acc chain (order identical to v1-v3).
#pragma unroll
    for (int k = 0; k < 4; ++k)
#pragma unroll
      for (int ni = 0; ni < 4; ++ni) {
        acc[0][ni] = __builtin_amdgcn_mfma_f32_16x16x32_bf16(
            af[0][k], b[k][ni], acc[0][ni], 0, 0, 0);
        acc[1][ni] = __builtin_amdgcn_mfma_f32_16x16x32_bf16(
            af[1][k], b[k][ni], acc[1][ni], 0, 0, 0);
      }
  }
#undef ALOAD

  // C/D: col = fl (e offset), row = fq*4 + r per 16-row fragment.
#pragma unroll
  for (int mf = 0; mf < 2; ++mf)
#pragma unroll
    for (int ni = 0; ni < 4; ++ni)
#pragma unroll
      for (int r = 0; r < 4; ++r) {
        const int mg = mbase + mf * 16 + fq * 4 + r;
        if (mg < M_total)
          outp[(size_t)mg * HD + ehw + ni * 16 + fl] = acc[mf][ni][r];
      }
}

// Fallback path if ws is too small for the weight transpose.
__global__ void tail_kernel(const int* __restrict__ cu, int num_seqs,
                            float* __restrict__ tail) {
  if (threadIdx.x == 0) {
    int acc = 0;
    tail[0] = 0.0f;
    for (int b = 0; b < num_seqs; ++b) {
      int n = cu[b + 1] - cu[b];
      acc += (n - BS) / STRIDE;
      tail[b + 1] = (float)acc;
    }
  }
}

__global__ void kvc_naive(const float* __restrict__ kp, const float* __restrict__ vp,
                          const float* __restrict__ wk, const float* __restrict__ wv,
                          const int* __restrict__ cu, int num_seqs,
                          float* __restrict__ out, long out_half) {
  int o = blockIdx.x, h = blockIdx.y, mat = blockIdx.z;
  int e = threadIdx.x;
  int acc = 0, base = -1;
  for (int b = 0; b < num_seqs; ++b) {
    int n = cu[b + 1] - cu[b];
    int ol = (n - BS) / STRIDE;
    if (o < acc + ol) { base = cu[b] + (o - acc) * STRIDE; break; }
    acc += ol;
  }
  if (base < 0) return;
  const float* x = mat ? vp : kp;
  const float* w = mat ? wv : wk;
  float s = 0.f;
  for (int j = 0; j < BS; ++j)
    for (int d = 0; d < HD; ++d)
      s += x[(size_t)(base + j) * (NH * HD) + h * HD + d] * w[(j * HD + d) * HD + e];
  out[(size_t)mat * out_half + ((size_t)o * NH + h) * HD + e] = s;
}

extern "C" void kernel_launch(void* const* d_in, const int* in_sizes, int n_in,
                              void* d_out, int out_size, void* d_ws, size_t ws_size,
                              hipStream_t stream) {
  const float* kp = (const float*)d_in[0];
  const float* vp = (const float*)d_in[1];
  const float* wk = (const float*)d_in[2];
  const float* wv = (const float*)d_in[3];
  const int* cu = (const int*)d_in[4];
  const int num_seqs = in_sizes[4] - 1;
  float* out = (float*)d_out;

  const long total_out = ((long)out_size - (num_seqs + 1)) / (2L * NH * HD);
  const long out_half = total_out * NH * HD;
  const int M_total = (int)(total_out * NH);
  float* tail = out + 2 * out_half;

  const size_t need_ws = (size_t)2 * BS * HD * HD * sizeof(unsigned short);
  if (ws_size >= need_ws) {
    unsigned short* wt = (unsigned short*)d_ws;
    prep_kernel<<<2 * BS * 4 + 1, 256, 0, stream>>>(wk, wv, wt, cu, num_seqs, tail);
    dim3 grid((M_total + 63) / 64, 2);
    kvc_gemm<<<grid, 256, 0, stream>>>(kp, vp, wt, cu, out, out_half, M_total,
                                       num_seqs);
  } else {
    tail_kernel<<<1, 64, 0, stream>>>(cu, num_seqs, tail);
    dim3 grid((unsigned)total_out, NH, 2);
    kvc_naive<<<grid, HD, 0, stream>>>(kp, vp, wk, wv, cu, num_seqs, out, out_half);
  }
}

// Round 4
// 365.013 us; speedup vs baseline: 1.1651x; 1.1651x over previous
//
#include <hip/hip_runtime.h>

#define NH 4
#define HD 128
#define BS 32
#define STRIDE 16

typedef float  floatx4 __attribute__((ext_vector_type(4)));
typedef __bf16 bf16x8  __attribute__((ext_vector_type(8)));
typedef __bf16 bf16x2  __attribute__((ext_vector_type(2)));
typedef unsigned short u16x8 __attribute__((ext_vector_type(8)));

__device__ __forceinline__ unsigned short f2bf(float f) {
  unsigned u = __builtin_bit_cast(unsigned, f);
  u += 0x7FFFu + ((u >> 16) & 1u);   // RTNE (inputs finite)
  return (unsigned short)(u >> 16);
}

__device__ __forceinline__ bf16x8 cvt8(float4 lo, float4 hi) {
  bf16x8 r;
#if __has_builtin(__builtin_amdgcn_cvt_pk_bf16_f32)
  bf16x2 p0 = __builtin_bit_cast(bf16x2, __builtin_amdgcn_cvt_pk_bf16_f32(lo.x, lo.y));
  bf16x2 p1 = __builtin_bit_cast(bf16x2, __builtin_amdgcn_cvt_pk_bf16_f32(lo.z, lo.w));
  bf16x2 p2 = __builtin_bit_cast(bf16x2, __builtin_amdgcn_cvt_pk_bf16_f32(hi.x, hi.y));
  bf16x2 p3 = __builtin_bit_cast(bf16x2, __builtin_amdgcn_cvt_pk_bf16_f32(hi.z, hi.w));
  r[0] = p0[0]; r[1] = p0[1]; r[2] = p1[0]; r[3] = p1[1];
  r[4] = p2[0]; r[5] = p2[1]; r[6] = p3[0]; r[7] = p3[1];
#else
  u16x8 t;
  t[0] = f2bf(lo.x); t[1] = f2bf(lo.y); t[2] = f2bf(lo.z); t[3] = f2bf(lo.w);
  t[4] = f2bf(hi.x); t[5] = f2bf(hi.y); t[6] = f2bf(hi.z); t[7] = f2bf(hi.w);
  r = __builtin_bit_cast(bf16x8, t);
#endif
  return r;
}

__device__ __forceinline__ void gld16(const unsigned short* g, unsigned short* l) {
  __builtin_amdgcn_global_load_lds(
      (const __attribute__((address_space(1))) unsigned int*)(g),
      (__attribute__((address_space(3))) unsigned int*)(l), 16, 0, 0);
}

// Prep: LDS-tiled transpose of w into wt layout [mat][j][k0][fq][e][dq] (bf16).
// Block 256 (last) writes the cu_out prefix tail.
__global__ void prep_kernel(const float* __restrict__ wk, const float* __restrict__ wv,
                            unsigned short* __restrict__ wt,
                            const int* __restrict__ cu, int num_seqs,
                            float* __restrict__ tail) {
  const int bx = blockIdx.x;
  if (bx == 2 * BS * 4) {
    if (threadIdx.x == 0) {
      int acc = 0;
      tail[0] = 0.0f;
      for (int b = 0; b < num_seqs; ++b) {
        int n = cu[b + 1] - cu[b];
        acc += (n - BS) / STRIDE;
        tail[b + 1] = (float)acc;
      }
    }
    return;
  }
  const int mat = bx >> 7;
  const int j   = (bx >> 2) & 31;
  const int k0  = bx & 3;
  const float* __restrict__ w =
      (mat ? wv : wk) + (size_t)j * (HD * HD) + (size_t)k0 * 32 * HD;
  __shared__ unsigned short tile[32][HD];
  const int t = threadIdx.x;
  const int r = t >> 3, c = (t & 7) * 16;
#pragma unroll
  for (int i = 0; i < 16; i += 4) {
    float4 f = *(const float4*)(w + r * HD + c + i);
    tile[r][c + i + 0] = f2bf(f.x);
    tile[r][c + i + 1] = f2bf(f.y);
    tile[r][c + i + 2] = f2bf(f.z);
    tile[r][c + i + 3] = f2bf(f.w);
  }
  __syncthreads();
  unsigned short* dst =
      wt + (size_t)mat * (BS * HD * HD) + (size_t)j * 16384 + k0 * 4096;
#pragma unroll
  for (int it = 0; it < 2; ++it) {
    int fi = t + it * 256;      // 0..511 over (fq, e)
    int fq = fi >> 7, e = fi & 127;
    u16x8 fr;
#pragma unroll
    for (int dq = 0; dq < 8; ++dq) fr[dq] = tile[fq * 8 + dq][e];
    *(u16x8*)(dst + fq * 1024 + e * 8) = fr;
  }
}

// Main GEMM, v5: depth-2 pipeline. Block = 64m x 64n (4 waves x 16m), B
// triple-buffered in 3 distinct 16KB LDS arrays (compile-time rotation,
// 6-unrolled), ONE barrier per step. At step j: wait step j-2's batch
// (vmcnt(12): 4 gld16 + 8 A-dwordx4 per wave), barrier, cvt A(j), issue
// B/A for j+2, 16 MFMA. Prefetch distance = 2 steps > HBM latency; the
// loop never drains vmcnt to 0. x-blocks paired so both n-halves of an
// m-tile land on the same XCD (A dedup in L2).
// K-order (j asc, k0 asc) identical -> bit-identical output.
__global__ __launch_bounds__(256, 1) void kvc_gemm(
    const float* __restrict__ kp, const float* __restrict__ vp,
    const unsigned short* __restrict__ wt, const int* __restrict__ cu,
    float* __restrict__ out, long out_half, int M_total, int num_seqs) {

  __shared__ __align__(16) unsigned short Bs0[8192];   // 16 KB
  __shared__ __align__(16) unsigned short Bs1[8192];   // 16 KB
  __shared__ __align__(16) unsigned short Bs2[8192];   // 16 KB

  // Decode x -> (m-tile, n-half) with pair-mates 8 apart (same XCD under
  // round-robin dispatch): xcd = x&7, nh = (x>>3)&1, mtg = x>>4.
  const int xcd = blockIdx.x & 7;
  const int nh2 = (blockIdx.x >> 3) & 1;
  const int mtg = blockIdx.x >> 4;
  const int mt  = mtg * 8 + xcd;
  if (mt * 64 >= M_total) return;
  const int e0 = nh2 * 64;

  const int mat = blockIdx.y;
  const float* __restrict__ x = mat ? vp : kp;
  const unsigned short* __restrict__ wmat = wt + (size_t)mat * (BS * HD * HD);
  float* __restrict__ outp = out + (size_t)mat * out_half;

  const int tid = threadIdx.x, wid = tid >> 6, lane = tid & 63;
  const int fl = lane & 15, fq = lane >> 4;
  const int mbase = mt * 64 + wid * 16;

  // Per-lane token base for this wave's 16-row m-fragment.
  int m = mbase + fl;
  int mc = m < M_total ? m : M_total - 1;
  int o = mc >> 2, h = mc & 3;
  int tb = 0, accb = 0;
  for (int b = 0; b < num_seqs; ++b) {
    int c0 = cu[b], c1 = cu[b + 1];
    int ol = (c1 - c0 - BS) / STRIDE;
    if (o >= accb && o - accb < ol) tb = c0 + (o - accb) * STRIDE;
    accb += ol;
  }
  const float* __restrict__ arow = x + ((size_t)tb * NH + h) * HD + fq * 8;

  floatx4 acc[4];
#pragma unroll
  for (int ni = 0; ni < 4; ++ni) acc[ni] = (floatx4){0.f, 0.f, 0.f, 0.f};

  float4 a[2][8];   // [parity][k0*2+half] - depth-2 A prefetch

  // Stage the e0-half of j-slice into BW: 4 gld16/lane. Chunk c = wid*4+i
  // maps to (k0 = c>>2, fq = c&3); each wave-instr moves 1KB contiguous.
#define BSTAGE(J, BW)                                                       \
  {                                                                         \
    _Pragma("unroll") for (int i_ = 0; i_ < 4; ++i_) {                      \
      const int c_ = wid * 4 + i_;                                          \
      const unsigned short* s_ = wmat + (size_t)(J) * 16384 +               \
          (c_ >> 2) * 4096 + (c_ & 3) * 1024 + (e0 + lane) * 8;             \
      gld16(s_, &BW[c_ * 512 + lane * 8]);                                  \
    }                                                                       \
  }

  // Prefetch A for column JN into parity P: 8 dwordx4/lane.
#define ALOAD(JN, P)                                                        \
  {                                                                         \
    const float* ar_ = arow + (size_t)(JN) * (NH * HD);                     \
    _Pragma("unroll") for (int k_ = 0; k_ < 4; ++k_) {                      \
      a[(P)][2 * k_]     = *(const float4*)(ar_ + k_ * 32);                 \
      a[(P)][2 * k_ + 1] = *(const float4*)(ar_ + k_ * 32 + 4);             \
    }                                                                       \
  }

#define VWAIT_(N) asm volatile("s_waitcnt vmcnt(" #N ")" ::: "memory")
#define VWAIT(N) VWAIT_(N)

  // Step j: drain step j-2's 12 ops (B(j) in LDS, A(j) in regs), barrier
  // (all waves' stages landed; also fences step j-1 reads of BW), cvt A(j)
  // (frees a[P] for the j+2 prefetch), issue j+2, compute.
#define STEP(J, BR, BW, P, NV, PRE)                                         \
  {                                                                         \
    VWAIT(NV);                                                              \
    __builtin_amdgcn_sched_barrier(0);                                      \
    __builtin_amdgcn_s_barrier();                                           \
    __builtin_amdgcn_sched_barrier(0);                                      \
    bf16x8 af_[4];                                                          \
    _Pragma("unroll") for (int k_ = 0; k_ < 4; ++k_)                        \
        af_[k_] = cvt8(a[(P)][2 * k_], a[(P)][2 * k_ + 1]);                 \
    if (PRE) {                                                              \
      BSTAGE((J) + 2, BW);                                                  \
      ALOAD((J) + 2, P);                                                    \
    }                                                                       \
    _Pragma("unroll") for (int k_ = 0; k_ < 4; ++k_) {                      \
      _Pragma("unroll") for (int ni_ = 0; ni_ < 4; ++ni_) {                 \
        bf16x8 bf_ = *(const bf16x8*)&BR[k_ * 2048 + fq * 512 +             \
                                         (ni_ * 16 + fl) * 8];              \
        acc[ni_] = __builtin_amdgcn_mfma_f32_16x16x32_bf16(                 \
            af_[k_], bf_, acc[ni_], 0, 0, 0);                               \
      }                                                                     \
    }                                                                       \
  }

  // Prologue: 2 steps in flight ({B0,A0}, {B1,A1} = 2 batches of 12).
  BSTAGE(0, Bs0);
  ALOAD(0, 0);
  BSTAGE(1, Bs1);
  ALOAD(1, 1);

  for (int jb = 0; jb < 30; jb += 6) {
    STEP(jb + 0, Bs0, Bs2, 0, 12, 1);
    STEP(jb + 1, Bs1, Bs0, 1, 12, 1);
    STEP(jb + 2, Bs2, Bs1, 0, 12, 1);
    STEP(jb + 3, Bs0, Bs2, 1, 12, 1);
    STEP(jb + 4, Bs1, Bs0, 0, 12, 1);
    STEP(jb + 5, Bs2, Bs1, 1, 12, 1);
  }
  STEP(30, Bs0, Bs2, 0, 12, 0);
  STEP(31, Bs1, Bs0, 1, 0, 0);

#undef STEP
#undef VWAIT
#undef VWAIT_
#undef ALOAD
#undef BSTAGE

  // C/D: col = fl (e offset within half), row = fq*4 + r.
#pragma unroll
  for (int ni = 0; ni < 4; ++ni) {
#pragma unroll
    for (int r = 0; r < 4; ++r) {
      const int mg = mbase + fq * 4 + r;
      if (mg < M_total)
        outp[(size_t)mg * HD + e0 + ni * 16 + fl] = acc[ni][r];
    }
  }
}

// Fallback path if ws is too small for the weight transpose.
__global__ void tail_kernel(const int* __restrict__ cu, int num_seqs,
                            float* __restrict__ tail) {
  if (threadIdx.x == 0) {
    int acc = 0;
    tail[0] = 0.0f;
    for (int b = 0; b < num_seqs; ++b) {
      int n = cu[b + 1] - cu[b];
      acc += (n - BS) / STRIDE;
      tail[b + 1] = (float)acc;
    }
  }
}

__global__ void kvc_naive(const float* __restrict__ kp, const float* __restrict__ vp,
                          const float* __restrict__ wk, const float* __restrict__ wv,
                          const int* __restrict__ cu, int num_seqs,
                          float* __restrict__ out, long out_half) {
  int o = blockIdx.x, h = blockIdx.y, mat = blockIdx.z;
  int e = threadIdx.x;
  int acc = 0, base = -1;
  for (int b = 0; b < num_seqs; ++b) {
    int n = cu[b + 1] - cu[b];
    int ol = (n - BS) / STRIDE;
    if (o < acc + ol) { base = cu[b] + (o - acc) * STRIDE; break; }
    acc += ol;
  }
  if (base < 0) return;
  const float* x = mat ? vp : kp;
  const float* w = mat ? wv : wk;
  float s = 0.f;
  for (int j = 0; j < BS; ++j)
    for (int d = 0; d < HD; ++d)
      s += x[(size_t)(base + j) * (NH * HD) + h * HD + d] * w[(j * HD + d) * HD + e];
  out[(size_t)mat * out_half + ((size_t)o * NH + h) * HD + e] = s;
}

extern "C" void kernel_launch(void* const* d_in, const int* in_sizes, int n_in,
                              void* d_out, int out_size, void* d_ws, size_t ws_size,
                              hipStream_t stream) {
  const float* kp = (const float*)d_in[0];
  const float* vp = (const float*)d_in[1];
  const float* wk = (const float*)d_in[2];
  const float* wv = (const float*)d_in[3];
  const int* cu = (const int*)d_in[4];
  const int num_seqs = in_sizes[4] - 1;
  float* out = (float*)d_out;

  const long total_out = ((long)out_size - (num_seqs + 1)) / (2L * NH * HD);
  const long out_half = total_out * NH * HD;
  const int M_total = (int)(total_out * NH);
  float* tail = out + 2 * out_half;

  const size_t need_ws = (size_t)2 * BS * HD * HD * sizeof(unsigned short);
  if (ws_size >= need_ws) {
    unsigned short* wt = (unsigned short*)d_ws;
    prep_kernel<<<2 * BS * 4 + 1, 256, 0, stream>>>(wk, wv, wt, cu, num_seqs, tail);
    const int mt_tiles = (M_total + 63) / 64;
    const int mtg = (mt_tiles + 7) / 8;
    dim3 grid(mtg * 16, 2);
    kvc_gemm<<<grid, 256, 0, stream>>>(kp, vp, wt, cu, out, out_half, M_total,
                                       num_seqs);
  } else {
    tail_kernel<<<1, 64, 0, stream>>>(cu, num_seqs, tail);
    dim3 grid((unsigned)total_out, NH, 2);
    kvc_naive<<<grid, HD, 0, stream>>>(kp, vp, wk, wv, cu, num_seqs, out, out_half);
  }
}